// Round 7
// baseline (13690.280 us; speedup 1.0000x reference)
//
#include <hip/hip_runtime.h>
#include <math.h>

#define N_NODES 10000
#define N_EDGES 320000

// persistent-grid geometry (r1/r6-proven co-resident): 512 blocks x 512 threads
// = 4096 waves, __launch_bounds__(512,4) -> 4 waves/SIMD -> 2 blocks/CU x 256.
#define NBLK 512
#define NTHR 512
#define NWAVES 4096

// ---------------- barrier / sync state ----------------
struct alignas(256) PadInt { int v; int _p[63]; };
struct Bar { PadInt leaf[16]; PadInt root; PadInt go[16]; };   // 33 * 256 B
// per layer: global barrier + per-XCD registration counters + per-XCD local barriers
struct LayerSync { Bar bar; PadInt xcnt[8]; PadInt xbar[8]; }; // 49 * 256 B
#define SYNC_INTS ((int)(sizeof(LayerSync) / 4))               // 3136
#define REGION_INTS (3 * SYNC_INTS + 64)                       // + abort word

// ---------------- setup kernels ----------------

__global__ void k_init(float* deg, int* cnt, int* fill, int* barmem, int n) {
    int i = blockIdx.x * blockDim.x + threadIdx.x;
    if (i < n) { deg[i] = 0.f; cnt[i] = 0; fill[i] = 0; }
    if (i < REGION_INTS) barmem[i] = 0;   // grid is 10240 threads >= 9472
}

__global__ void k_deg(const int* __restrict__ ei, const float* __restrict__ w,
                      float* deg, int E) {
    int e = blockIdx.x * blockDim.x + threadIdx.x;
    if (e < E) atomicAdd(&deg[ei[e]], w[e]);
}

__global__ void k_dis(float* deg, int n) {
    int i = blockIdx.x * blockDim.x + threadIdx.x;
    if (i < n) {
        float d = deg[i];
        deg[i] = (d > 0.f) ? (float)(1.0 / sqrt((double)d)) : 0.f;
    }
}

__global__ void k_norm(const int* __restrict__ ei, const float* __restrict__ w,
                       const float* __restrict__ dis, float* __restrict__ normw,
                       int* cnt, int E) {
    int e = blockIdx.x * blockDim.x + threadIdx.x;
    if (e < E) {
        int s = ei[e], d = ei[E + e];
        normw[e] = -dis[s] * w[e] * dis[d];
        atomicAdd(&cnt[d], 1);
    }
}

// single-block exclusive scan over counts -> rowptr[0..n]
__global__ void k_scan(const int* __restrict__ cnt, int* __restrict__ rowptr, int n) {
    __shared__ int part[1024];
    const int PER = 10;
    int t = threadIdx.x;
    int base = t * PER;
    int local[PER];
    int s = 0;
    for (int j = 0; j < PER; j++) {
        int idx = base + j;
        int v = (idx < n) ? cnt[idx] : 0;
        local[j] = v; s += v;
    }
    part[t] = s;
    __syncthreads();
    for (int off = 1; off < 1024; off <<= 1) {
        int v = part[t];
        int u = (t >= off) ? part[t - off] : 0;
        __syncthreads();
        part[t] = v + u;
        __syncthreads();
    }
    int excl = (t > 0) ? part[t - 1] : 0;
    for (int j = 0; j < PER; j++) {
        int idx = base + j;
        if (idx < n) rowptr[idx] = excl;
        excl += local[j];
    }
    if (t == 1023) rowptr[n] = part[1023];
}

// pair CSR: {src byte-offset (stride-64 rows), norm bits}
__global__ void k_fill(const int* __restrict__ ei, const float* __restrict__ normw,
                       const int* __restrict__ rowptr, int* fill,
                       int2* __restrict__ pr, int E) {
    int e = blockIdx.x * blockDim.x + threadIdx.x;
    if (e < E) {
        int d = ei[E + e];
        int pos = atomicAdd(&fill[d], 1);
        int idx = rowptr[d] + pos;
        pr[idx] = make_int2(ei[e] << 8, __float_as_int(normw[e]));
    }
}

// ---------------- coherent access helpers ----------------
// sc1 agent-scope relaxed atomics: bypass L1/L2, serviced at the coherence
// point (r6-proven correct for cross-XCD publish/consume).
__device__ __forceinline__ void pub4(float* p, float v) {
    __hip_atomic_store(p, v, __ATOMIC_RELAXED, __HIP_MEMORY_SCOPE_AGENT);
}
template <bool COH>
__device__ __forceinline__ float ld4(const char* p) {
    if constexpr (COH)
        return __hip_atomic_load((const float*)(const void*)p,
                                 __ATOMIC_RELAXED, __HIP_MEMORY_SCOPE_AGENT);
    else
        return *(const float*)(const void*)p;
}

// real XCD id (HW-verified on MI355X: returns 0..7)
__device__ __forceinline__ int get_xcd() {
    int x;
    asm volatile("s_getreg_b32 %0, hwreg(HW_REG_XCC_ID)" : "=s"(x));
    return x & 7;
}

// 8 batched sc0 loads (L1-bypass, L2-CACHED) + one waitcnt.
// L1 bypass required: tloc hot lines are rewritten each step by other CUs'
// copy stores, which do not invalidate this CU's L1.
__device__ __forceinline__ void load8_sc0(const unsigned long long* a, float* v) {
    asm volatile(
        "global_load_dword %0, %8, off sc0\n\t"
        "global_load_dword %1, %9, off sc0\n\t"
        "global_load_dword %2, %10, off sc0\n\t"
        "global_load_dword %3, %11, off sc0\n\t"
        "global_load_dword %4, %12, off sc0\n\t"
        "global_load_dword %5, %13, off sc0\n\t"
        "global_load_dword %6, %14, off sc0\n\t"
        "global_load_dword %7, %15, off sc0\n\t"
        "s_waitcnt vmcnt(0)"
        : "=&v"(v[0]), "=&v"(v[1]), "=&v"(v[2]), "=&v"(v[3]),
          "=&v"(v[4]), "=&v"(v[5]), "=&v"(v[6]), "=&v"(v[7])
        : "v"(a[0]), "v"(a[1]), "v"(a[2]), "v"(a[3]),
          "v"(a[4]), "v"(a[5]), "v"(a[6]), "v"(a[7])
        : "memory");
}

// ---------------- grid barrier (fence-free, r6-proven) ----------------
__device__ __forceinline__ bool gridbar(Bar* __restrict__ B, int* __restrict__ abortf,
                                        int phase) {
    __shared__ int ok_s;
    asm volatile("s_waitcnt vmcnt(0)" ::: "memory");
    __syncthreads();
    if (threadIdx.x == 0) {
        int s = blockIdx.x & 15;
        int old = __hip_atomic_fetch_add(&B->leaf[s].v, 1,
                                         __ATOMIC_RELAXED, __HIP_MEMORY_SCOPE_AGENT);
        if (old + 1 == phase * (NBLK / 16)) {
            int r = __hip_atomic_fetch_add(&B->root.v, 1,
                                           __ATOMIC_RELAXED, __HIP_MEMORY_SCOPE_AGENT);
            if (r + 1 == phase * 16) {
#pragma unroll
                for (int j = 0; j < 16; j++)
                    __hip_atomic_store(&B->go[j].v, phase,
                                       __ATOMIC_RELAXED, __HIP_MEMORY_SCOPE_AGENT);
            }
        }
        int ok = 1, spins = 0;
        while (__hip_atomic_load(&B->go[s].v, __ATOMIC_RELAXED,
                                 __HIP_MEMORY_SCOPE_AGENT) < phase) {
            __builtin_amdgcn_s_sleep(2);
            if ((++spins & 255) == 0) {
                if (__hip_atomic_load(abortf, __ATOMIC_RELAXED,
                                      __HIP_MEMORY_SCOPE_AGENT)) { ok = 0; break; }
                if (spins > (1 << 19)) {
                    __hip_atomic_store(abortf, 1, __ATOMIC_RELAXED,
                                       __HIP_MEMORY_SCOPE_AGENT);
                    ok = 0; break;
                }
            }
        }
        ok_s = ok;
    }
    __syncthreads();
    return ok_s != 0;
}

// ---------------- per-XCD local barrier ----------------
// target = phase * (number of blocks registered on this XCD)
__device__ __forceinline__ bool localbar(PadInt* __restrict__ xb,
                                         int* __restrict__ abortf, int target) {
    __shared__ int lok_s;
    asm volatile("s_waitcnt vmcnt(0)" ::: "memory");
    __syncthreads();
    if (threadIdx.x == 0) {
        __hip_atomic_fetch_add(&xb->v, 1, __ATOMIC_RELAXED, __HIP_MEMORY_SCOPE_AGENT);
        int ok = 1, spins = 0;
        while (__hip_atomic_load(&xb->v, __ATOMIC_RELAXED,
                                 __HIP_MEMORY_SCOPE_AGENT) < target) {
            __builtin_amdgcn_s_sleep(1);
            if ((++spins & 255) == 0) {
                if (__hip_atomic_load(abortf, __ATOMIC_RELAXED,
                                      __HIP_MEMORY_SCOPE_AGENT)) { ok = 0; break; }
                if (spins > (1 << 19)) {
                    __hip_atomic_store(abortf, 1, __ATOMIC_RELAXED,
                                       __HIP_MEMORY_SCOPE_AGENT);
                    ok = 0; break;
                }
            }
        }
        lok_s = ok;
    }
    __syncthreads();
    return lok_s != 0;
}

// ---------------- gathers ----------------
// wide, plain-cached (K01 only: hin is immutable during the kernel)
__device__ __forceinline__ float gather_w_cached(const char* __restrict__ tb,
                                                 const int2* __restrict__ pr,
                                                 int rb, int dg, int lane4) {
    float agg = 0.f;
    int e = 0;
    for (; e + 8 <= dg; e += 8) {
        int2 p[8]; float v[8];
#pragma unroll
        for (int u = 0; u < 8; u++) p[u] = pr[rb + e + u];
#pragma unroll
        for (int u = 0; u < 8; u++)
            v[u] = *(const float*)(tb + (unsigned)p[u].x + lane4);
#pragma unroll
        for (int u = 0; u < 8; u++)
            agg = fmaf(__int_as_float(p[u].y), v[u], agg);
    }
    if (e < dg) {
        int2 p[8]; float v[8];
#pragma unroll
        for (int u = 0; u < 8; u++) p[u] = pr[(e + u < dg) ? (rb + e + u) : rb];
#pragma unroll
        for (int u = 0; u < 8; u++)
            v[u] = *(const float*)(tb + (unsigned)p[u].x + lane4);
#pragma unroll
        for (int u = 0; u < 8; u++) {
            float w = (e + u < dg) ? __int_as_float(p[u].y) : 0.f;
            agg = fmaf(w, v[u], agg);
        }
    }
    return agg;
}

// wide, from the XCD-private mirror: sc0 loads (L1-bypass, L2-cached)
__device__ __forceinline__ float gather_w_loc(const float* __restrict__ tloc,
                                              const int2* __restrict__ pr,
                                              int rb, int dg, int lane4) {
    unsigned long long base = (unsigned long long)(uintptr_t)tloc + (unsigned)lane4;
    float agg = 0.f;
    int e = 0;
    for (; e + 8 <= dg; e += 8) {
        int2 p[8]; unsigned long long a[8]; float v[8];
#pragma unroll
        for (int u = 0; u < 8; u++) p[u] = pr[rb + e + u];
#pragma unroll
        for (int u = 0; u < 8; u++) a[u] = base + (unsigned)p[u].x;
        load8_sc0(a, v);
#pragma unroll
        for (int u = 0; u < 8; u++)
            agg = fmaf(__int_as_float(p[u].y), v[u], agg);
    }
    if (e < dg) {
        int2 p[8]; unsigned long long a[8]; float v[8];
#pragma unroll
        for (int u = 0; u < 8; u++) p[u] = pr[(e + u < dg) ? (rb + e + u) : rb];
#pragma unroll
        for (int u = 0; u < 8; u++) a[u] = base + (unsigned)p[u].x;
        load8_sc0(a, v);
#pragma unroll
        for (int u = 0; u < 8; u++) {
            float w = (e + u < dg) ? __int_as_float(p[u].y) : 0.f;
            agg = fmaf(w, v[u], agg);
        }
    }
    return agg;
}

// narrow (stride-4 float rows): r6-proven sc1-direct path
template <bool COH>
__device__ __forceinline__ float gather_n(const char* __restrict__ tb,
                                          const int2* __restrict__ pr,
                                          int rb, int dg, int lc4, int eo) {
    float agg = 0.f;
    int e = eo;
    for (; e + 32 <= dg; e += 32) {
        int2 p0 = pr[rb + e];
        int2 p1 = pr[rb + e + 16];
        float v0 = ld4<COH>(tb + ((unsigned)p0.x >> 4) + lc4);
        float v1 = ld4<COH>(tb + ((unsigned)p1.x >> 4) + lc4);
        agg = fmaf(__int_as_float(p0.y), v0, agg);
        agg = fmaf(__int_as_float(p1.y), v1, agg);
    }
    for (; e < dg; e += 16) {
        int2 p = pr[rb + e];
        agg = fmaf(__int_as_float(p.y),
                   ld4<COH>(tb + ((unsigned)p.x >> 4) + lc4), agg);
    }
    agg += __shfl_xor(agg, 4);
    agg += __shfl_xor(agg, 8);
    agg += __shfl_xor(agg, 16);
    agg += __shfl_xor(agg, 32);
    return agg;
}

// ---------------- dense: acc(lane=o) += sum_c t2(c) * W[c][o] ----------------
template <int CI, int CO>
__device__ __forceinline__ void dense(float& acc, float t2v,
                                      const float* __restrict__ Wk, int lane) {
#pragma unroll
    for (int c = 0; c < CI; c++) {
        float tb = __int_as_float(__builtin_amdgcn_readlane(__float_as_int(t2v), c));
        float wv;
        if (CO < 64) wv = (lane < CO) ? Wk[c * CO + lane] : 0.f;
        else         wv = Wk[c * CO + lane];
        acc = fmaf(tb, wv, acc);
    }
}

// ---------------- persistent WIDE layer (XCD-mirror design) ----------------
// Per step: [copy PUB -> tloc[xcd] (sc1 loads, plain stores -> local L2)]
// -> local barrier -> [gather from tloc via sc0 (L2-cached), compute, publish
// T_k to PUB[k&1] via sc1] -> global barrier. acc/T-own stay in registers.
template <int CI, int CO, int KK, int LAST>
__global__ __launch_bounds__(NTHR, 4) void layer_wide(
    const int* __restrict__ rowptr, const int2* __restrict__ pr,
    const float* __restrict__ hin,
    float* __restrict__ pubA, float* __restrict__ pubB,
    float* __restrict__ tlocAll,
    const float* __restrict__ W, const float* __restrict__ bias,
    const float* __restrict__ W4, float* __restrict__ outp,
    Bar* __restrict__ bar, PadInt* __restrict__ xcnt, PadInt* __restrict__ xbar,
    int* __restrict__ abortf)
{
    int tid = threadIdx.x;
    int lane = tid & 63;
    int lane4 = lane * 4;
    int xcd = get_xcd();
    __shared__ int sh_idx, sh_cnt;
    if (tid == 0)
        sh_idx = __hip_atomic_fetch_add(&xcnt[xcd].v, 1,
                                        __ATOMIC_RELAXED, __HIP_MEMORY_SCOPE_AGENT);
    __syncthreads();
    float* tloc = tlocAll + (size_t)xcd * (N_NODES * 64);

    int wid = blockIdx.x * (NTHR / 64) + (tid >> 6);  // 0..4095
    int n0 = wid;
    int n1 = wid + NWAVES;
    bool has2 = wid < (N_NODES - 2 * NWAVES);  // < 1808
    int n2 = wid + 2 * NWAVES;

    int rb0 = rowptr[n0], dg0 = rowptr[n0 + 1] - rb0;
    int rb1 = rowptr[n1], dg1 = rowptr[n1 + 1] - rb1;
    int rb2 = 0, dg2 = 0;
    if (has2) { rb2 = rowptr[n2]; dg2 = rowptr[n2 + 1] - rb2; }

    float acc0, acc1, acc2 = 0.f;
    float p0, p1, p2 = 0.f;   // T_{k-2} own value
    float q0, q1, q2 = 0.f;   // T_{k-1} own value

#define K01W(nid, rb, dg, acc, t0v, t1v) {                                  \
        float hr = hin[(nid) * 64 + lane];                                  \
        float a = (lane < CO) ? bias[lane] : 0.f;                           \
        dense<CI, CO>(a, hr, W, lane);                                      \
        float g = gather_w_cached((const char*)hin, pr, rb, dg, lane4);     \
        dense<CI, CO>(a, g, W + CI * CO, lane);                             \
        pub4(&pubB[(nid) * 64 + lane], g);                                  \
        acc = a; t0v = hr; t1v = g; }

#define STEPW(nid, rb, dg, acc, t0v, t1v) {                                 \
        float g = gather_w_loc(tloc, pr, rb, dg, lane4);                    \
        float t2 = fmaf(2.f, g, -t0v);                                      \
        dense<CI, CO>(acc, t2, Wk, lane);                                   \
        if (!lastk) { pub4(&wpub[(nid) * 64 + lane], t2); t0v = t1v; t1v = t2; } }

    int gph = 0, lph = 0;
    K01W(n0, rb0, dg0, acc0, p0, q0);
    K01W(n1, rb1, dg1, acc1, p1, q1);
    if (has2) K01W(n2, rb2, dg2, acc2, p2, q2);
    if (!gridbar(bar, abortf, ++gph)) return;

    // all blocks registered before gbar#1 completed -> count is final
    if (tid == 0)
        sh_cnt = __hip_atomic_load(&xcnt[xcd].v,
                                   __ATOMIC_RELAXED, __HIP_MEMORY_SCOPE_AGENT);
    __syncthreads();
    const int myidx = sh_idx, mycnt = sh_cnt;
    const int TOT64 = N_NODES * 64 / 2;  // u64 count of a PUB buffer
    const int c0 = (int)((long long)myidx * TOT64 / mycnt);
    const int c1 = (int)((long long)(myidx + 1) * TOT64 / mycnt);
    unsigned long long* dloc64 = (unsigned long long*)tloc;

    for (int k = 2; k < KK; k++) {
        const float* csrc = ((k - 1) & 1) ? pubB : pubA;  // PUB[(k-1)&1]
        float* wpub = (k & 1) ? pubB : pubA;              // PUB[k&1]
        const float* Wk = W + (size_t)k * (CI * CO);
        const bool lastk = (k == KK - 1);

        // copy my slice of PUB -> XCD mirror (sc1 loads, plain L2 stores)
        const unsigned long long* s64 = (const unsigned long long*)csrc;
        for (int i = c0 + tid; i < c1; i += NTHR)
            dloc64[i] = __hip_atomic_load(s64 + i, __ATOMIC_RELAXED,
                                          __HIP_MEMORY_SCOPE_AGENT);
        if (!localbar(&xbar[xcd], abortf, (++lph) * mycnt)) return;

        STEPW(n0, rb0, dg0, acc0, p0, q0);
        STEPW(n1, rb1, dg1, acc1, p1, q1);
        if (has2) STEPW(n2, rb2, dg2, acc2, p2, q2);
        if (!lastk) { if (!gridbar(bar, abortf, ++gph)) return; }
    }

#define EPIW(nid, acc) {                                           \
        float a = acc;                                             \
        if (LAST == 1) {                                           \
            outp[(nid) * 64 + lane] = a / (1.f + expf(-a));        \
        } else {                                                   \
            float h = a / (1.f + expf(-a));                        \
            float w4 = (lane < 30) ? W4[lane] : 0.f;               \
            float pp = h * w4;                                     \
            pp += __shfl_xor(pp, 1);                               \
            pp += __shfl_xor(pp, 2);                               \
            pp += __shfl_xor(pp, 4);                               \
            pp += __shfl_xor(pp, 8);                               \
            pp += __shfl_xor(pp, 16);                              \
            pp += __shfl_xor(pp, 32);                              \
            if (lane == 0) outp[nid] = 1.f / (1.f + expf(-pp));    \
        } }

    EPIW(n0, acc0);
    EPIW(n1, acc1);
    if (has2) EPIW(n2, acc2);
#undef K01W
#undef STEPW
#undef EPIW
}

// ---------------- persistent NARROW layer (r6-proven sc1-direct) ----------------
template <int KK>
__global__ __launch_bounds__(NTHR, 4) void layer_narrow(
    const int* __restrict__ rowptr, const int2* __restrict__ pr,
    const float* __restrict__ xin,
    float* __restrict__ tA, float* __restrict__ tB,
    const float* __restrict__ W, const float* __restrict__ bias,
    float* __restrict__ outp,
    Bar* __restrict__ bar, int* __restrict__ abortf)
{
    int tid = threadIdx.x;
    int lane = tid & 63;
    int lc = lane & 3, eo = lane >> 2, lc4 = lc * 4;
    int wid = blockIdx.x * (NTHR / 64) + (tid >> 6);

    int n0 = wid;
    int n1 = wid + NWAVES;
    bool has2 = wid < (N_NODES - 2 * NWAVES);
    int n2 = wid + 2 * NWAVES;

    int rb0 = rowptr[n0], dg0 = rowptr[n0 + 1] - rb0;
    int rb1 = rowptr[n1], dg1 = rowptr[n1 + 1] - rb1;
    int rb2 = 0, dg2 = 0;
    if (has2) { rb2 = rowptr[n2]; dg2 = rowptr[n2 + 1] - rb2; }

    float acc0, acc1, acc2 = 0.f;
    float p0, p1, p2 = 0.f;
    float q0, q1, q2 = 0.f;

#define K01N(nid, rb, dg, acc, t0v, t1v) {                               \
        float xr = xin[(nid) * 4 + lc];                                  \
        float a = bias[lane];                                            \
        dense<4, 64>(a, xr, W, lane);                                    \
        float g = gather_n<false>((const char*)xin, pr, rb, dg, lc4, eo);\
        dense<4, 64>(a, g, W + 4 * 64, lane);                            \
        if (lane < 4) pub4(&tB[(nid) * 4 + lane], g);                    \
        acc = a; t0v = xr; t1v = g; }

#define STEPN(nid, rb, dg, acc, t0v, t1v) {                              \
        float g = gather_n<true>((const char*)rd, pr, rb, dg, lc4, eo);  \
        float t2 = fmaf(2.f, g, -t0v);                                   \
        dense<4, 64>(acc, t2, Wk, lane);                                 \
        if (!lastk) {                                                    \
            if (lane < 4) pub4(&wr[(nid) * 4 + lane], t2);               \
            t0v = t1v; t1v = t2; } }

    int phase = 0;
    K01N(n0, rb0, dg0, acc0, p0, q0);
    K01N(n1, rb1, dg1, acc1, p1, q1);
    if (has2) K01N(n2, rb2, dg2, acc2, p2, q2);
    if (!gridbar(bar, abortf, ++phase)) return;

    for (int k = 2; k < KK; k++) {
        const float* rd = (k & 1) ? tA : tB;
        float* wr = (k & 1) ? tB : tA;
        const float* Wk = W + (size_t)k * (4 * 64);
        const bool lastk = (k == KK - 1);
        STEPN(n0, rb0, dg0, acc0, p0, q0);
        STEPN(n1, rb1, dg1, acc1, p1, q1);
        if (has2) STEPN(n2, rb2, dg2, acc2, p2, q2);
        if (!lastk) { if (!gridbar(bar, abortf, ++phase)) return; }
    }

    outp[n0 * 64 + lane] = acc0 / (1.f + expf(-acc0));
    outp[n1 * 64 + lane] = acc1 / (1.f + expf(-acc1));
    if (has2) outp[n2 * 64 + lane] = acc2 / (1.f + expf(-acc2));
#undef K01N
#undef STEPN
}

// ---------------- host ----------------

extern "C" void kernel_launch(void* const* d_in, const int* in_sizes, int n_in,
                              void* d_out, int out_size, void* d_ws, size_t ws_size,
                              hipStream_t stream) {
    const float* x  = (const float*)d_in[0];
    const int*   ei = (const int*)d_in[1];
    const float* ew = (const float*)d_in[2];
    const float* W1 = (const float*)d_in[3];
    const float* b1 = (const float*)d_in[4];
    const float* W2 = (const float*)d_in[5];
    const float* b2 = (const float*)d_in[6];
    const float* W3 = (const float*)d_in[7];
    const float* b3 = (const float*)d_in[8];
    const float* W4 = (const float*)d_in[9];
    float* out = (float*)d_out;

    const int n = N_NODES, E = N_EDGES;

    char* ws = (char*)d_ws;
    size_t off = 0;
    auto alloc = [&](size_t bytes) -> void* {
        void* p = ws + off;
        off += (bytes + 255) & ~(size_t)255;
        return p;
    };
    float* deg    = (float*)alloc(n * 4);     // becomes dis in-place
    int*   cnt    = (int*)alloc(n * 4);
    int*   fill   = (int*)alloc(n * 4);
    int*   rowptr = (int*)alloc((n + 4) * 4);
    float* normw  = (float*)alloc((size_t)E * 4);
    int2*  pr     = (int2*)alloc((size_t)E * 8);
    int*   barmem = (int*)alloc(REGION_INTS * 4);
    float* t4a  = (float*)alloc(n * 4 * 4);
    float* t4b  = (float*)alloc(n * 4 * 4);
    float* tba  = (float*)alloc((size_t)n * 64 * 4);   // wide PUB[0]
    float* tbb  = (float*)alloc((size_t)n * 64 * 4);   // wide PUB[1]
    float* tloc = (float*)alloc((size_t)8 * n * 64 * 4);  // per-XCD mirrors
    float* h1   = (float*)alloc((size_t)n * 64 * 4);
    float* h2   = (float*)alloc((size_t)n * 64 * 4);
    (void)ws_size; (void)n_in; (void)in_sizes; (void)out_size;

    LayerSync* L = (LayerSync*)barmem;
    int* abortf = barmem + 3 * SYNC_INTS;

    // ---- preprocessing: degree, norm, dst-sorted pair-CSR ----
    k_init<<<(n + 255) / 256, 256, 0, stream>>>(deg, cnt, fill, barmem, n);
    k_deg <<<(E + 255) / 256, 256, 0, stream>>>(ei, ew, deg, E);
    k_dis <<<(n + 255) / 256, 256, 0, stream>>>(deg, n);
    k_norm<<<(E + 255) / 256, 256, 0, stream>>>(ei, ew, deg, normw, cnt, E);
    k_scan<<<1, 1024, 0, stream>>>(cnt, rowptr, n);
    k_fill<<<(E + 255) / 256, 256, 0, stream>>>(ei, normw, rowptr, fill, pr, E);

    // ---- Layer 1: K=120, 4 -> 64, silu -> h1 (persistent, sc1-direct) ----
    layer_narrow<120><<<NBLK, NTHR, 0, stream>>>(
        rowptr, pr, x, t4a, t4b, W1, b1, h1, &L[0].bar, abortf);

    // ---- Layer 2: K=120, 64 -> 60, silu -> h2 (persistent, XCD-mirror) ----
    layer_wide<64, 60, 120, 1><<<NBLK, NTHR, 0, stream>>>(
        rowptr, pr, h1, tba, tbb, tloc, W2, b2, nullptr, h2,
        &L[1].bar, L[1].xcnt, L[1].xbar, abortf);

    // ---- Layer 3 (K=20, 60 -> 30, silu) + fused Layer 4 (30 -> 1, sigmoid) ----
    layer_wide<60, 30, 20, 2><<<NBLK, NTHR, 0, stream>>>(
        rowptr, pr, h2, tba, tbb, tloc, W3, b3, W4, out,
        &L[2].bar, L[2].xcnt, L[2].xbar, abortf);
}